// Round 6
// baseline (155.091 us; speedup 1.0000x reference)
//
#include <hip/hip_runtime.h>

#define NTOK 2048
#define BATCH 2
#define FIN 128
#define FEMB 64

typedef __attribute__((ext_vector_type(8))) short short8;
typedef __attribute__((ext_vector_type(4))) float floatx4;

#define MFMA_B16(a, b, c) __builtin_amdgcn_mfma_f32_16x16x32_bf16((a), (b), (c), 0, 0, 0)

// f32 -> bf16 bits (RNE)
static __device__ __forceinline__ unsigned short f2bf_bits(float f) {
    unsigned u = __float_as_uint(f);
    unsigned r = u + 0x7FFFu + ((u >> 16) & 1u);
    return (unsigned short)(r >> 16);
}
static __device__ __forceinline__ float bfbits2f(unsigned short h) {
    return __uint_as_float(((unsigned)h) << 16);
}

// ws stat block layout (uints): [0,128) cent f32-bits (atomicAdd float),
// [128,256) colmin (init +inf), [256,384) colmax (init 0)
// ============ K1: XwT[64][4096] = bf16(W)^T (64x128) @ bf16(x)^T (128x4096) =
// n-tile 32, grid 128. Block 0 zero-inits ALL 384 stat words (256-thr block:
// two guarded stores — round-5 bug left colmax[0..127] poisoned).
#define K1S 152   // 128+24 shorts: rows differ by 12 dword-banks -> <=2-way, free
__global__ __launch_bounds__(256) void k_gemm_xwT(const float* __restrict__ x,
                                                  const float* __restrict__ W,
                                                  unsigned short* __restrict__ XwT,
                                                  unsigned* __restrict__ stats) {
    __shared__ unsigned short As[64 * K1S];   // WT[f][k]
    __shared__ unsigned short Bs[32 * K1S];   // x token rows [n][k]
    int t = threadIdx.x;
    int n0 = blockIdx.x * 32;
    if (blockIdx.x == 0) {
        // cent[0,128)=0 ; colmin[128,256)=+inf ; colmax[256,384)=0
        stats[t] = (t >= 128) ? 0x7F800000u : 0u;         // t in [0,256)
        if (t < 128) stats[256 + t] = 0u;                 // colmax
    }
    // W: 128x64 f32 (L2-resident) -> transposed bf16 in LDS
#pragma unroll
    for (int c = 0; c < 32; ++c) {
        int idx = c * 256 + t;
        int k = idx >> 6, f = idx & 63;
        As[f * K1S + k] = f2bf_bits(W[idx]);
    }
    // x tile: 32 tokens x 128 feat f32 -> bf16
#pragma unroll
    for (int c = 0; c < 2; ++c) {
        int e = c * 2048 + t * 8;
        int row = e >> 7, col = e & 127;
        const float* src = &x[(size_t)(n0 + row) * FIN + col];
        float4 f0 = *(const float4*)src;
        float4 f1 = *(const float4*)(src + 4);
        unsigned short h[8] = {f2bf_bits(f0.x), f2bf_bits(f0.y), f2bf_bits(f0.z),
                               f2bf_bits(f0.w), f2bf_bits(f1.x), f2bf_bits(f1.y),
                               f2bf_bits(f1.z), f2bf_bits(f1.w)};
        *(uint4*)&Bs[row * K1S + col] = *(uint4*)h;
    }
    __syncthreads();
    int w = t >> 6, l = t & 63, lm = l & 15, lq = l >> 4;
    floatx4 acc[2] = {};
#pragma unroll
    for (int kk = 0; kk < 128; kk += 32) {
        short8 a = *(const short8*)&As[(w * 16 + lm) * K1S + kk + lq * 8];
#pragma unroll
        for (int ct = 0; ct < 2; ++ct) {
            short8 b = *(const short8*)&Bs[(ct * 16 + lm) * K1S + kk + lq * 8];
            acc[ct] = MFMA_B16(a, b, acc[ct]);
        }
    }
#pragma unroll
    for (int ct = 0; ct < 2; ++ct)
#pragma unroll
        for (int r = 0; r < 4; ++r) {
            int f = w * 16 + lq * 4 + r;
            int tok = n0 + ct * 16 + lm;
            XwT[(size_t)f * (BATCH * NTOK) + tok] = f2bf_bits(acc[ct][r]);
        }
}

// ============ K2: x_emb = relu(A @ Xw + b); LDS-free streaming GEMM =========
// 512 thr (8 waves), each wave owns K-range w*256..+256; no barriers in loop.
// Epilogue: cross-wave f32 reduce in LDS; emit xemb f32 + bf16, q rowsums,
// centroid atomicAdd + column min/max atomics (for the scale). grid (128, 2).
#define RP 66     // 64+2 f32: wave-partial row stride (2-way banks, free)
__global__ __launch_bounds__(512) void k_gemm_xemb(const float* __restrict__ A,
                                                   const unsigned short* __restrict__ XwT,
                                                   const float* __restrict__ bvec,
                                                   float* __restrict__ xemb_out,
                                                   unsigned short* __restrict__ xebf,
                                                   float* __restrict__ q,
                                                   unsigned* __restrict__ stats) {
    __shared__ float red[8][16][RP];   // 33.8 KB
    int t = threadIdx.x;
    int m0 = blockIdx.x * 16, b = blockIdx.y;
    int w = t >> 6, l = t & 63, lm = l & 15, lq = l >> 4;
    const float* Arow =
        A + (size_t)b * NTOK * NTOK + (size_t)(m0 + lm) * NTOK + w * 256 + lq * 8;
    const unsigned short* Bbase = XwT + b * NTOK + w * 256 + lq * 8;  // + f*4096
    floatx4 acc[4] = {};
#pragma unroll
    for (int kk = 0; kk < 256; kk += 32) {
        float4 a0 = *(const float4*)(Arow + kk);
        float4 a1 = *(const float4*)(Arow + kk + 4);
        unsigned short h[8] = {f2bf_bits(a0.x), f2bf_bits(a0.y), f2bf_bits(a0.z),
                               f2bf_bits(a0.w), f2bf_bits(a1.x), f2bf_bits(a1.y),
                               f2bf_bits(a1.z), f2bf_bits(a1.w)};
        short8 af = *(short8*)h;
#pragma unroll
        for (int ct = 0; ct < 4; ++ct) {
            short8 bf = *(const short8*)(Bbase + (size_t)(ct * 16 + lm) * (BATCH * NTOK) + kk);
            acc[ct] = MFMA_B16(af, bf, acc[ct]);
        }
    }
#pragma unroll
    for (int ct = 0; ct < 4; ++ct)
#pragma unroll
        for (int r = 0; r < 4; ++r)
            red[w][lq * 4 + r][ct * 16 + lm] = acc[ct][r];
    __syncthreads();
    // thread t: row r = t>>5 (16 rows), cols c0 = (t&31)*2 (+1)
    int r = t >> 5, c0 = (t & 31) * 2;
    float v0 = 0.f, v1 = 0.f;
#pragma unroll
    for (int ww = 0; ww < 8; ++ww) {
        v0 += red[ww][r][c0];
        v1 += red[ww][r][c0 + 1];
    }
    v0 = fmaxf(v0 + bvec[c0], 0.0f);
    v1 = fmaxf(v1 + bvec[c0 + 1], 0.0f);
    size_t o = (size_t)b * NTOK * FEMB + (size_t)(m0 + r) * FEMB + c0;
    *(float2*)&xemb_out[o] = make_float2(v0, v1);
    unsigned short h0 = f2bf_bits(v0), h1 = f2bf_bits(v1);
    *(unsigned*)&xebf[o] = (unsigned)h0 | ((unsigned)h1 << 16);
    float d0 = bfbits2f(h0), d1 = bfbits2f(h1);
    float s = d0 * d0 + d1 * d1;   // row-sumsq partial (2 cols)
#pragma unroll
    for (int off = 16; off; off >>= 1) s += __shfl_xor(s, off, 64);  // 32-lane group
    if ((t & 31) == 0) q[b * NTOK + m0 + r] = s;
    __syncthreads();               // red reads done; reuse red[0] as vb[16][RP]
    red[0][r][c0] = v0;
    red[0][r][c0 + 1] = v1;
    __syncthreads();
    if (t < 64) {
        float cs = 0.f, mn = red[0][0][t], mxv = mn;
#pragma unroll
        for (int rr = 0; rr < 16; ++rr) {
            float v = red[0][rr][t];
            cs += v;
            mn = fminf(mn, v);
            mxv = fmaxf(mxv, v);
        }
        atomicAdd((float*)&stats[b * 64 + t], cs);          // centroid sum
        atomicMin(&stats[128 + b * 64 + t], __float_as_uint(mn));   // v>=0: bit-monotone
        atomicMax(&stats[256 + b * 64 + t], __float_as_uint(mxv));
    }
}

// ============ K3: adjacency (z<2) + edge_index (z>=2) fused =================
// D = s^2 * relu(q_m + q_n - 2<e_m,e_n>)  (centroid cancels; s = 0.9/mx,
// mx = max_{b,f} max(colmax-c, c-colmin) computed inline from stats)
#define K5S 88
__global__ __launch_bounds__(256) void k_adj_edges(const unsigned short* __restrict__ xebf,
                                                   const float* __restrict__ q,
                                                   const unsigned* __restrict__ stats,
                                                   const float* __restrict__ temp,
                                                   const float* __restrict__ thr,
                                                   float* __restrict__ wout,
                                                   float* __restrict__ eout) {
    int z = blockIdx.z;
    if (z >= 2) {   // ---- edge_index: 16,777,216 f32 over 512 blocks ----
        int eb = (z - 2) * 256 + blockIdx.y * 16 + blockIdx.x;
        long base0 = (long)eb * 32768 + threadIdx.x * 4;
#pragma unroll
        for (int j = 0; j < 32; ++j) {
            long g = base0 + (long)j * 1024;
            float4 v;
            if (g < 8388608L) {                  // rows: idx // N (const over 4)
                float rr = (float)(g >> 11);
                v.x = rr; v.y = rr; v.z = rr; v.w = rr;
            } else {                             // cols: idx % N + N*batch
                long rel = g - 8388608L;
                int c0 = (int)(rel & 2047);      // 4-aligned, no wrap
                int add = ((int)(rel >> 22)) << 11;
                v.x = (float)(c0 + 0 + add);
                v.y = (float)(c0 + 1 + add);
                v.z = (float)(c0 + 2 + add);
                v.w = (float)(c0 + 3 + add);
            }
            *(float4*)&eout[g] = v;
        }
        return;
    }
    // ---- adjacency: 128x128 tile, K=64 single shot ----
    __shared__ unsigned short As[128 * K5S];
    __shared__ unsigned short Bs[128 * K5S];
    int t = threadIdx.x;
    int m0 = blockIdx.x * 128, n0 = blockIdx.y * 128, b = z;
    // inline global scale from stats (per-wave redundant, no barrier)
    float sc;
    {
        int l = t & 63;
        float m = 0.f;
#pragma unroll
        for (int b2 = 0; b2 < 2; ++b2) {
            float c = __uint_as_float(stats[b2 * 64 + l]) * (1.0f / NTOK);
            float hi = __uint_as_float(stats[256 + b2 * 64 + l]);
            float lo = __uint_as_float(stats[128 + b2 * 64 + l]);
            m = fmaxf(m, fmaxf(hi - c, c - lo));
        }
#pragma unroll
        for (int off = 32; off; off >>= 1) m = fmaxf(m, __shfl_xor(m, off, 64));
        sc = 0.9f / m;
    }
    float s2 = sc * sc;
    const unsigned short* xb = xebf + (size_t)b * NTOK * FEMB;
#pragma unroll
    for (int c = 0; c < 4; ++c) {
        int e = c * 2048 + t * 8;
        int row = e >> 6, col = e & 63;
        *(uint4*)&As[row * K5S + col] = *(const uint4*)&xb[(size_t)(m0 + row) * FEMB + col];
        *(uint4*)&Bs[row * K5S + col] = *(const uint4*)&xb[(size_t)(n0 + row) * FEMB + col];
    }
    __syncthreads();
    int w = t >> 6, l = t & 63, lm = l & 15, lq = l >> 4;
    floatx4 acc[2][8] = {};
#pragma unroll
    for (int kk = 0; kk < 64; kk += 32) {
        short8 a0 = *(const short8*)&As[((w * 2 + 0) * 16 + lm) * K5S + kk + lq * 8];
        short8 a1 = *(const short8*)&As[((w * 2 + 1) * 16 + lm) * K5S + kk + lq * 8];
#pragma unroll
        for (int ct = 0; ct < 8; ++ct) {
            short8 bb = *(const short8*)&Bs[(ct * 16 + lm) * K5S + kk + lq * 8];
            acc[0][ct] = MFMA_B16(a0, bb, acc[0][ct]);
            acc[1][ct] = MFMA_B16(a1, bb, acc[1][ct]);
        }
    }
    float tval = temp[0];
    float ath = fabsf(thr[0]);
    float qm[2][4], qn[8];
#pragma unroll
    for (int rt = 0; rt < 2; ++rt)
#pragma unroll
        for (int r = 0; r < 4; ++r)
            qm[rt][r] = q[b * NTOK + m0 + (w * 2 + rt) * 16 + lq * 4 + r];
#pragma unroll
    for (int ct = 0; ct < 8; ++ct) qn[ct] = q[b * NTOK + n0 + ct * 16 + lm];
    float* wob = wout + (size_t)b * NTOK * NTOK;
#pragma unroll
    for (int rt = 0; rt < 2; ++rt)
#pragma unroll
        for (int r = 0; r < 4; ++r) {
            int m = m0 + (w * 2 + rt) * 16 + lq * 4 + r;
#pragma unroll
            for (int ct = 0; ct < 8; ++ct) {
                float g = acc[rt][ct][r];
                float D = s2 * fmaxf(qm[rt][r] + qn[ct] - 2.0f * g, 0.0f);
                float z2 = tval * (ath - D);
                float wgt = 1.0f / (1.0f + __expf(-z2));
                wob[(size_t)m * NTOK + n0 + ct * 16 + lm] = wgt;
            }
        }
}

extern "C" void kernel_launch(void* const* d_in, const int* in_sizes, int n_in,
                              void* d_out, int out_size, void* d_ws, size_t ws_size,
                              hipStream_t stream) {
    const float* x    = (const float*)d_in[0];   // [2,2048,128] f32
    const float* A    = (const float*)d_in[1];   // [2,2048,2048] f32
    const float* W    = (const float*)d_in[2];   // [128,64] f32
    const float* bvec = (const float*)d_in[3];   // [64] f32
    const float* temp = (const float*)d_in[4];   // scalar f32
    const float* thr  = (const float*)d_in[5];   // scalar f32
    float* out = (float*)d_out;                  // x_emb | edge_index | weights
    char* ws = (char*)d_ws;

    unsigned short* XwT   = (unsigned short*)(ws + 0);        // 64x4096 bf16 (512 KB)
    unsigned*       stats = (unsigned*)(ws + 524288);         // cent|min|max (384 u32)
    unsigned short* xebf  = (unsigned short*)(ws + 525824);   // 4096x64 bf16 (512 KB)
    float*          q     = (float*)(ws + 1050112);           // 4096 f32

    float* xemb_out = out;                       // [0, 262144)
    float* edge_out = out + 262144;              // [262144, 17039360)
    float* wgt_out  = out + 262144 + 16777216;   // [17039360, 25427968)

    k_gemm_xwT<<<128, 256, 0, stream>>>(x, W, XwT, stats);
    k_gemm_xemb<<<dim3(128, 2), 512, 0, stream>>>(A, XwT, bvec, xemb_out, xebf, q, stats);
    k_adj_edges<<<dim3(16, 16, 4), 256, 0, stream>>>(xebf, q, stats, temp, thr,
                                                     wgt_out, edge_out);
}